// Round 6
// baseline (711.443 us; speedup 1.0000x reference)
//
#include <hip/hip_runtime.h>
#include <math.h>

#define G 2
#define BB 2
#define L 1024
#define DM 256
#define DI 512
#define DS 16
#define DR 16
#define CH 64              // chunks per sequence
#define CL 16              // L / CH
#define RTOT (G*BB*L)      // 4096 rows per layer-step
#define YSTR 520           // Ys LDS row stride (shorts)
#define XSTR 520           // xc LDS row stride (shorts)

#define NWIN  (4 * 2 * DI * DM)   // in_proj elements (4 layers)
#define NWOUT (4 * DM * DI)       // out_proj elements
#define NWX   (4 * 48 * DI)       // x_proj elements (4 layers)

typedef short bh8 __attribute__((ext_vector_type(8)));
typedef float f4x __attribute__((ext_vector_type(4)));

#define MFMA16 __builtin_amdgcn_mfma_f32_16x16x32_bf16

__device__ __forceinline__ float silu_f(float x) { return x / (1.f + __expf(-x)); }
__device__ __forceinline__ float softplus_f(float x) {
    return (x > 20.f) ? x : __logf(1.f + __expf(x));
}

__device__ __forceinline__ unsigned short f2bf(float f) {
    unsigned u = __float_as_uint(f);
    unsigned r = u + 0x7FFFu + ((u >> 16) & 1u);
    return (unsigned short)(r >> 16);
}
__device__ __forceinline__ float bf2f(unsigned short s) {
    return __uint_as_float(((unsigned)s) << 16);
}
__device__ __forceinline__ void split4s(float4 v, short4& h, short4& l) {
    unsigned short s;
    s = f2bf(v.x); h.x = (short)s; l.x = (short)f2bf(v.x - bf2f(s));
    s = f2bf(v.y); h.y = (short)s; l.y = (short)f2bf(v.y - bf2f(s));
    s = f2bf(v.z); h.z = (short)s; l.z = (short)f2bf(v.z - bf2f(s));
    s = f2bf(v.w); h.w = (short)s; l.w = (short)f2bf(v.w - bf2f(s));
}

// ---------------------------------------------------------------------------
// in_proj MFMA GEMM (3xbf16). BM=128, BN=64, K=256. grid (16,32) = 512 blocks.
// AMAP 1 (step 0): A = x (fp32, time reversal), B = fp32 split on the fly;
//   epilogue: one-time weight pre-split (in/out/x_proj) + zero sync counters.
// AMAP 0 (step 1): A = Pout pre-split bf16 hi/lo, B = pre-split Wih/Wil.
// ---------------------------------------------------------------------------
template<int AMAP>
__global__ __launch_bounds__(256) void mfma_inproj(
    const float* __restrict__ Ax,
    const short* __restrict__ APh, const short* __restrict__ APl,
    const float* __restrict__ WinF,
    const short* __restrict__ Wh, const short* __restrict__ Wl,
    int step, float* __restrict__ C,
    const float* __restrict__ cvtA, short* __restrict__ cAh, short* __restrict__ cAl, int n4a,
    const float* __restrict__ cvtB, short* __restrict__ cBh, short* __restrict__ cBl, int n4b,
    const float* __restrict__ cvtC, short* __restrict__ cCh, short* __restrict__ cCl, int n4c,
    unsigned* __restrict__ Ctr)
{
    constexpr int BM = 128, Ktot = DM, Nout = 2 * DI, ldc = 1024;
    __shared__ short As_hi[BM * 40];
    __shared__ short As_lo[BM * 40];
    __shared__ short Bs_hi[64 * 40];
    __shared__ short Bs_lo[64 * 40];

    const int row0 = blockIdx.y * BM;
    const int col0 = blockIdx.x * 64;
    const int g    = row0 >> 11;
    const int lay  = g * 2 + step;
    const short* Whg = Wh  + (size_t)lay * Nout * Ktot;
    const short* Wlg = Wl  + (size_t)lay * Nout * Ktot;
    const float* WFg = WinF + (size_t)lay * Nout * Ktot;
    const int t    = threadIdx.x;
    const int lane = t & 63, wv = t >> 6;
    const int m = lane & 15, quad = lane >> 4;
    const int wr = wv >> 1, wc = wv & 1;
    const int NT = Ktot / 32;     // 8

    float4 pa[4];
    short4 pah[4], pal[4], pbh[2], pbl[2];
    float4 pbf[2];
    auto loadT = [&](int kt) {
        const int kb = kt * 32;
        #pragma unroll
        for (int i = 0; i < 4; i++) {
            int id = t + 256 * i;
            int row = id >> 3, kq = id & 7;
            if (AMAP == 1) {
                int gr = row0 + row;
                int gg = gr >> 11, b = (gr >> 10) & 1, l = gr & 1023;
                int sl = gg ? (1023 - l) : l;
                pa[i] = *(const float4*)&Ax[(size_t)(b * 1024 + sl) * Ktot + kb + kq * 4];
            } else {
                size_t o = (size_t)(row0 + row) * Ktot + kb + kq * 4;
                pah[i] = *(const short4*)&APh[o];
                pal[i] = *(const short4*)&APl[o];
            }
        }
        #pragma unroll
        for (int i = 0; i < 2; i++) {
            int id = t + 256 * i;
            int row = id >> 3, kq = id & 7;
            if (AMAP == 1) {
                pbf[i] = *(const float4*)&WFg[(size_t)(col0 + row) * Ktot + kb + kq * 4];
            } else {
                size_t o = (size_t)(col0 + row) * Ktot + kb + kq * 4;
                pbh[i] = *(const short4*)&Whg[o];
                pbl[i] = *(const short4*)&Wlg[o];
            }
        }
    };

    f4x acc[4][2] = {};
    loadT(0);

    for (int kt = 0; kt < NT; kt++) {
        #pragma unroll
        for (int i = 0; i < 4; i++) {
            int id = t + 256 * i;
            int row = id >> 3, kq = id & 7;
            if (AMAP == 1) {
                short4 h4, l4; split4s(pa[i], h4, l4);
                *(short4*)&As_hi[row * 40 + kq * 4] = h4;
                *(short4*)&As_lo[row * 40 + kq * 4] = l4;
            } else {
                *(short4*)&As_hi[row * 40 + kq * 4] = pah[i];
                *(short4*)&As_lo[row * 40 + kq * 4] = pal[i];
            }
        }
        #pragma unroll
        for (int i = 0; i < 2; i++) {
            int id = t + 256 * i;
            int row = id >> 3, kq = id & 7;
            if (AMAP == 1) {
                short4 h4, l4; split4s(pbf[i], h4, l4);
                *(short4*)&Bs_hi[row * 40 + kq * 4] = h4;
                *(short4*)&Bs_lo[row * 40 + kq * 4] = l4;
            } else {
                *(short4*)&Bs_hi[row * 40 + kq * 4] = pbh[i];
                *(short4*)&Bs_lo[row * 40 + kq * 4] = pbl[i];
            }
        }
        __syncthreads();
        if (kt + 1 < NT) loadT(kt + 1);

        bh8 ah[4], al[4], bh[2], bl[2];
        #pragma unroll
        for (int p = 0; p < 4; p++) {
            int r = wr * 64 + p * 16 + m;
            ah[p] = *(bh8*)&As_hi[r * 40 + quad * 8];
            al[p] = *(bh8*)&As_lo[r * 40 + quad * 8];
        }
        #pragma unroll
        for (int q = 0; q < 2; q++) {
            int r = wc * 32 + q * 16 + m;
            bh[q] = *(bh8*)&Bs_hi[r * 40 + quad * 8];
            bl[q] = *(bh8*)&Bs_lo[r * 40 + quad * 8];
        }
        #pragma unroll
        for (int p = 0; p < 4; p++)
            #pragma unroll
            for (int q = 0; q < 2; q++) {
                acc[p][q] = MFMA16(ah[p], bh[q], acc[p][q], 0, 0, 0);
                acc[p][q] = MFMA16(ah[p], bl[q], acc[p][q], 0, 0, 0);
                acc[p][q] = MFMA16(al[p], bh[q], acc[p][q], 0, 0, 0);
            }
        __syncthreads();
    }

    #pragma unroll
    for (int p = 0; p < 4; p++)
        #pragma unroll
        for (int q = 0; q < 2; q++) {
            int gcol = col0 + wc * 32 + q * 16 + m;
            #pragma unroll
            for (int r = 0; r < 4; r++) {
                int grow = row0 + wr * 64 + p * 16 + quad * 4 + r;
                C[(size_t)grow * ldc + gcol] = acc[p][q][r];
            }
        }

    // ---- folded one-time work (step 0 only): weight pre-split + ctr zero ----
    if (AMAP == 1) {
        const int bid = blockIdx.y * 16 + blockIdx.x;      // 0..511
        if (bid == 0 && t < 16) Ctr[t] = 0u;               // sync counters
        const int ntot = n4a + n4b + n4c;
        for (int i = bid * 256 + t; i < ntot; i += 512 * 256) {
            int j = i; const float* W; short *H, *Lo;
            if (j < n4a) { W = cvtA; H = cAh; Lo = cAl; }
            else if (j < n4a + n4b) { j -= n4a; W = cvtB; H = cBh; Lo = cBl; }
            else { j -= n4a + n4b; W = cvtC; H = cCh; Lo = cCl; }
            float4 v = *(const float4*)&W[(size_t)j * 4];
            short4 h4, l4; split4s(v, h4, l4);
            *(short4*)&H[(size_t)j * 4] = h4;
            *(short4*)&Lo[(size_t)j * 4] = l4;
        }
    }
}

// ---------------------------------------------------------------------------
// scanAB: fused scanA + distributed combine + scanB in ONE dispatch.
// 256 blocks (one per (gb,chunk)), all co-resident (cooperative launch).
// Sync: per-gb atomic counters + s_sleep spin (NOT grid.sync).
//   phase A: conv+silu (xc regs+LDS) -> x_proj MFMA (dbl LDS) -> dt (regs) ->
//            chunk-local scan -> Aprod/Hend; threadfence; ctrA[gb]++.
//   combine: spin ctrA==64; each block scans d-slice [c*8,c*8+8) over CH
//            chunks -> Hinit; threadfence; ctrB[gb]++.
//   phase B: spin ctrB==64; replay with Hinit (dbl/xc/dt persist in LDS/regs),
//            y -> Ys LDS, fused out_proj MFMA epilogue.
// ---------------------------------------------------------------------------
template<int OUTMODE>
__global__ __launch_bounds__(512) void scanAB(
    const float* __restrict__ XZ, const float* __restrict__ cw,
    const float* __restrict__ cb,
    const short* __restrict__ Wxh, const short* __restrict__ Wxl,
    const float* __restrict__ A_log, const float* __restrict__ Wdt,
    const float* __restrict__ bdt, const float* __restrict__ Dp,
    float* __restrict__ Aprod, float* __restrict__ Hend,
    float* __restrict__ Hinit,
    unsigned* __restrict__ ctrA, unsigned* __restrict__ ctrB,
    const short* __restrict__ Woh, const short* __restrict__ Wol,
    float* __restrict__ Cout, short* __restrict__ Ph, short* __restrict__ Pl,
    int step)
{
    __shared__ float dbl[CL][48];                    // persists A -> B
    __shared__ __align__(16) char uni[57856];        // phase overlay
    short* xcH  = (short*)uni;                       // A: [CL*XSTR]
    short* xcL  = xcH + CL * XSTR;
    float* part = (float*)(uni + 33280);             // A: [8][CL][48]
    short* Ys_hi = (short*)uni;                      // B: [CL*YSTR]
    short* Ys_lo = Ys_hi + CL * YSTR;

    const int blk = blockIdx.x;
    const int c  = blk & (CH - 1);
    const int gb = blk >> 6;
    const int g  = gb >> 1;
    const int lay = g * 2 + step;
    const int d  = threadIdx.x;          // channel 0..511
    const int tid = threadIdx.x;
    const int r0 = gb * L + c * CL;
    const int lane = tid & 63, wv = tid >> 6;
    const int m = lane & 15, quad = lane >> 4;

    // ======== phase A ========
    float4 w4 = *(const float4*)&cw[((size_t)lay * DI + d) * 4];
    float cbv = cb[(size_t)lay * DI + d];
    float xzv[CL + 3];
    #pragma unroll
    for (int j = 0; j < CL + 3; j++) {
        int lr = c * CL + j - 3;
        xzv[j] = (lr < 0) ? 0.f : XZ[(size_t)(gb * L + lr) * 1024 + d];
    }
    float xc[CL];
    #pragma unroll
    for (int tt = 0; tt < CL; tt++) {
        float v = cbv + w4.x * xzv[tt] + w4.y * xzv[tt + 1]
                      + w4.z * xzv[tt + 2] + w4.w * xzv[tt + 3];
        v = silu_f(v);
        xc[tt] = v;
        unsigned short hs = f2bf(v);
        xcH[tt * XSTR + d] = (short)hs;
        xcL[tt * XSTR + d] = (short)f2bf(v - bf2f(hs));
    }
    __syncthreads();

    // x_proj MFMA: dbl[16][48] = xc @ Wx^T, split-K=64/wave
    {
        const int ks = wv * 64;
        const size_t wb = (size_t)lay * 48 * DI;
        f4x acc3[3] = {};
        #pragma unroll
        for (int kt = 0; kt < 2; kt++) {
            const int kb = ks + kt * 32 + quad * 8;
            bh8 ah = *(bh8*)&xcH[m * XSTR + kb];
            bh8 al = *(bh8*)&xcL[m * XSTR + kb];
            #pragma unroll
            for (int f = 0; f < 3; f++) {
                bh8 bh = *(const bh8*)&Wxh[wb + (size_t)(f * 16 + m) * DI + kb];
                bh8 bl = *(const bh8*)&Wxl[wb + (size_t)(f * 16 + m) * DI + kb];
                acc3[f] = MFMA16(ah, bh, acc3[f], 0, 0, 0);
                acc3[f] = MFMA16(ah, bl, acc3[f], 0, 0, 0);
                acc3[f] = MFMA16(al, bh, acc3[f], 0, 0, 0);
            }
        }
        #pragma unroll
        for (int f = 0; f < 3; f++)
            #pragma unroll
            for (int r = 0; r < 4; r++)
                part[(wv * CL + quad * 4 + r) * 48 + f * 16 + m] = acc3[f][r];
    }
    __syncthreads();

    for (int o = tid; o < CL * 48; o += 512) {
        int tt = o / 48, cc = o - tt * 48;
        float v = 0.f;
        #pragma unroll
        for (int w = 0; w < 8; w++) v += part[(w * CL + tt) * 48 + cc];
        dbl[tt][cc] = v;
    }

    float wdt[16];
    const float* wrow = Wdt + ((size_t)lay * DI + d) * DR;
    #pragma unroll
    for (int k = 0; k < 16; k += 4) {
        float4 v = *(const float4*)&wrow[k];
        wdt[k] = v.x; wdt[k + 1] = v.y; wdt[k + 2] = v.z; wdt[k + 3] = v.w;
    }
    float bias = bdt[(size_t)lay * DI + d];

    float a[DS], h[DS], ap[DS], dts[CL];
    const float* al = A_log + ((size_t)lay * DI + d) * DS;
    #pragma unroll
    for (int s = 0; s < DS; s++) { a[s] = -__expf(al[s]); h[s] = 0.f; ap[s] = 1.f; }
    __syncthreads();

    for (int tt = 0; tt < CL; tt++) {
        float dtr = bias;
        #pragma unroll
        for (int k = 0; k < 16; k++) dtr += dbl[tt][k] * wdt[k];
        float dt = softplus_f(dtr);
        dts[tt] = dt;
        float dx = dt * xc[tt];
        #pragma unroll
        for (int s = 0; s < DS; s++) {
            float da = __expf(dt * a[s]);
            h[s] = da * h[s] + dx * dbl[tt][16 + s];
            ap[s] *= da;
        }
    }
    size_t base = ((size_t)(gb * DI + d) * CH + c) * DS;
    #pragma unroll
    for (int q = 0; q < 4; q++) {
        *(float4*)&Aprod[base + q * 4] = make_float4(ap[q*4], ap[q*4+1], ap[q*4+2], ap[q*4+3]);
        *(float4*)&Hend [base + q * 4] = make_float4(h[q*4],  h[q*4+1],  h[q*4+2],  h[q*4+3]);
    }

    // publish phase A
    __threadfence();
    __syncthreads();
    if (tid == 0) atomicAdd(&ctrA[gb], 1u);

    // prefetch phase-B z while waiting
    float zz[CL];
    #pragma unroll
    for (int tt = 0; tt < CL; tt++) zz[tt] = XZ[(size_t)(r0 + tt) * 1024 + 512 + d];
    float Dv = Dp[(size_t)lay * DI + d];

    // ---- spin 1: all chunks of this gb published ----
    if (tid == 0) {
        unsigned it = 0;
        while (__hip_atomic_load(&ctrA[gb], __ATOMIC_RELAXED,
                                 __HIP_MEMORY_SCOPE_AGENT) < 64u &&
               ++it < (1u << 26)) __builtin_amdgcn_s_sleep(8);
    }
    __syncthreads();
    __threadfence();

    // ======== distributed combine: this block scans d-slice [c*8, c*8+8) ====
    if (tid < 128) {
        int dd = c * 8 + (tid >> 4);
        int ss = tid & 15;
        size_t b2 = (size_t)(gb * DI + dd) * CH * DS + ss;
        float hh = 0.f;
        for (int c0 = 0; c0 < CH; c0 += 8) {
            float apv[8], ev[8];
            #pragma unroll
            for (int j = 0; j < 8; j++) {
                size_t o = b2 + (size_t)(c0 + j) * DS;
                apv[j] = Aprod[o]; ev[j] = Hend[o];
            }
            #pragma unroll
            for (int j = 0; j < 8; j++) {
                Hinit[b2 + (size_t)(c0 + j) * DS] = hh;
                hh = apv[j] * hh + ev[j];
            }
        }
    }
    __threadfence();
    __syncthreads();
    if (tid == 0) atomicAdd(&ctrB[gb], 1u);

    // ---- spin 2: combine complete for this gb ----
    if (tid == 0) {
        unsigned it = 0;
        while (__hip_atomic_load(&ctrB[gb], __ATOMIC_RELAXED,
                                 __HIP_MEMORY_SCOPE_AGENT) < 64u &&
               ++it < (1u << 26)) __builtin_amdgcn_s_sleep(8);
    }
    __syncthreads();
    __threadfence();

    // ======== phase B ========
    #pragma unroll
    for (int q = 0; q < 4; q++) {
        float4 hv = *(const float4*)&Hinit[base + q * 4];
        h[q*4] = hv.x; h[q*4+1] = hv.y; h[q*4+2] = hv.z; h[q*4+3] = hv.w;
    }
    // NOTE: Ys overlays xcH/part; dbl is separate and persists.
    #pragma unroll
    for (int tt = 0; tt < CL; tt++) {
        float dt = dts[tt];
        float dx = dt * xc[tt];
        float y = 0.f;
        #pragma unroll
        for (int s = 0; s < DS; s++) {
            float da = __expf(dt * a[s]);
            h[s] = da * h[s] + dx * dbl[tt][16 + s];
            y += h[s] * dbl[tt][32 + s];
        }
        y += xc[tt] * Dv;
        y *= silu_f(zz[tt]);
        unsigned short hs = f2bf(y);
        Ys_hi[tt * YSTR + d] = (short)hs;
        Ys_lo[tt * YSTR + d] = (short)f2bf(y - bf2f(hs));
    }
    __syncthreads();

    // fused out_proj epilogue: 16 rows x 256 cols, K=512
    const size_t wbase = (size_t)lay * DM * DI;
    #pragma unroll
    for (int q = 0; q < 2; q++) {
        const int coln = wv * 32 + q * 16 + m;
        const size_t wrow2 = wbase + (size_t)coln * DI;
        bh8 wh[16], wl[16];
        #pragma unroll
        for (int i = 0; i < 16; i++) {
            const int kk = i * 32 + quad * 8;
            wh[i] = *(const bh8*)&Woh[wrow2 + kk];
            wl[i] = *(const bh8*)&Wol[wrow2 + kk];
        }
        f4x acc = {};
        #pragma unroll
        for (int i = 0; i < 16; i++) {
            const int kk = i * 32 + quad * 8;
            bh8 ahv = *(bh8*)&Ys_hi[m * YSTR + kk];
            bh8 alv = *(bh8*)&Ys_lo[m * YSTR + kk];
            acc = MFMA16(ahv, wh[i], acc, 0, 0, 0);
            acc = MFMA16(ahv, wl[i], acc, 0, 0, 0);
            acc = MFMA16(alv, wh[i], acc, 0, 0, 0);
        }
        #pragma unroll
        for (int r = 0; r < 4; r++) {
            int tt = quad * 4 + r;
            int grow = r0 + tt;
            if (OUTMODE == 0) {
                size_t o = (size_t)grow * DM + coln;
                unsigned short hs = f2bf(acc[r]);
                Ph[o] = (short)hs;
                Pl[o] = (short)f2bf(acc[r] - bf2f(hs));
            } else {
                int b = (grow >> 10) & 1, l = grow & 1023;
                size_t dst = (g == 0)
                    ? ((size_t)(b * 1024 + l) * 512 + coln)
                    : ((size_t)(b * 1024 + (1023 - l)) * 512 + 256 + coln);
                Cout[dst] = acc[r];
            }
        }
    }
}

extern "C" void kernel_launch(void* const* d_in, const int* in_sizes, int n_in,
                              void* d_out, int out_size, void* d_ws, size_t ws_size,
                              hipStream_t stream)
{
    const float* x        = (const float*)d_in[0];
    const float* in_proj  = (const float*)d_in[1];
    const float* conv_w   = (const float*)d_in[2];
    const float* conv_b   = (const float*)d_in[3];
    const float* x_proj   = (const float*)d_in[4];
    const float* dt_proj  = (const float*)d_in[5];
    const float* dt_bias  = (const float*)d_in[6];
    const float* A_log    = (const float*)d_in[7];
    const float* Dp       = (const float*)d_in[8];
    const float* out_proj = (const float*)d_in[9];
    float* out = (float*)d_out;

    float* w = (float*)d_ws;
    size_t o = 0;
    float* XZ    = w + o; o += (size_t)RTOT * 1024;
    float* Aprod = w + o; o += (size_t)G * BB * DI * CH * DS;
    float* Hend  = w + o; o += (size_t)G * BB * DI * CH * DS;
    float* Hinit = w + o; o += (size_t)G * BB * DI * CH * DS;
    short* Wih   = (short*)(w + o); o += NWIN / 2;
    short* Wil   = (short*)(w + o); o += NWIN / 2;
    short* Woh   = (short*)(w + o); o += NWOUT / 2;
    short* Wol   = (short*)(w + o); o += NWOUT / 2;
    short* Wxh   = (short*)(w + o); o += NWX / 2;
    short* Wxl   = (short*)(w + o); o += NWX / 2;
    short* Ph    = (short*)(w + o); o += (size_t)RTOT * DM / 2;
    short* Pl    = (short*)(w + o); o += (size_t)RTOT * DM / 2;
    o = (o + 63) & ~(size_t)63;
    unsigned* Ctr = (unsigned*)(w + o); o += 64;   // [step][round][gb] = 16 words
    (void)ws_size; (void)in_sizes; (void)n_in; (void)out_size;

    for (int step = 0; step < 2; step++) {
        // in_proj: 4096x1024, K=256, MFMA 3xbf16. 128x64 tiles -> 512 blocks.
        if (step == 0)
            mfma_inproj<1><<<dim3(16, 32), 256, 0, stream>>>(
                x, nullptr, nullptr, in_proj, nullptr, nullptr, 0, XZ,
                in_proj, Wih, Wil, NWIN / 4,
                out_proj, Woh, Wol, NWOUT / 4,
                x_proj, Wxh, Wxl, NWX / 4, Ctr);
        else
            mfma_inproj<0><<<dim3(16, 32), 256, 0, stream>>>(
                nullptr, Ph, Pl, nullptr, Wih, Wil, 1, XZ,
                nullptr, nullptr, nullptr, 0,
                nullptr, nullptr, nullptr, 0,
                nullptr, nullptr, nullptr, 0, nullptr);

        // fused scanA + combine + scanB (+out_proj): 256 blocks, cooperative.
        unsigned* ctrA = Ctr + step * 8;
        unsigned* ctrB = ctrA + 4;
        const float* XZc = XZ;
        const short *Wxhc = Wxh, *Wxlc = Wxl, *Wohc = Woh, *Wolc = Wol;
        float* Coutp = (step == 0) ? nullptr : out;
        short* Php = (step == 0) ? Ph : nullptr;
        short* Plp = (step == 0) ? Pl : nullptr;
        int stepv = step;
        void* kargs[] = {
            (void*)&XZc, (void*)&conv_w, (void*)&conv_b,
            (void*)&Wxhc, (void*)&Wxlc, (void*)&A_log, (void*)&dt_proj,
            (void*)&dt_bias, (void*)&Dp,
            (void*)&Aprod, (void*)&Hend, (void*)&Hinit,
            (void*)&ctrA, (void*)&ctrB,
            (void*)&Wohc, (void*)&Wolc,
            (void*)&Coutp, (void*)&Php, (void*)&Plp, (void*)&stepv };
        void* fn = (step == 0) ? reinterpret_cast<void*>(scanAB<0>)
                               : reinterpret_cast<void*>(scanAB<1>);
        hipError_t err = hipLaunchCooperativeKernel(
            fn, dim3(G * BB * CH), dim3(512), kargs, 0, stream);
        if (err != hipSuccess) {
            (void)hipGetLastError();
            // fallback: plain launch (256 blocks @ 1/CU are co-resident anyway)
            if (step == 0)
                scanAB<0><<<G * BB * CH, 512, 0, stream>>>(
                    XZ, conv_w, conv_b, Wxh, Wxl, A_log, dt_proj, dt_bias, Dp,
                    Aprod, Hend, Hinit, ctrA, ctrB, Woh, Wol,
                    nullptr, Ph, Pl, 0);
            else
                scanAB<1><<<G * BB * CH, 512, 0, stream>>>(
                    XZ, conv_w, conv_b, Wxh, Wxl, A_log, dt_proj, dt_bias, Dp,
                    Aprod, Hend, Hinit, ctrA, ctrB, Woh, Wol,
                    out, nullptr, nullptr, 1);
        }
    }
}

// Round 7
// 225.383 us; speedup vs baseline: 3.1566x; 3.1566x over previous
//
#include <hip/hip_runtime.h>
#include <math.h>

#define G 2
#define BB 2
#define L 1024
#define DM 256
#define DI 512
#define DS 16
#define DR 16
#define CH 64              // chunks per sequence
#define CL 16              // L / CH
#define RTOT (G*BB*L)      // 4096 rows per layer-step
#define YSTR 520           // Ys LDS row stride (shorts)
#define XSTR 520           // xc LDS row stride (shorts)

#define NWOUT (4 * DM * DI)       // out_proj elements (4 layers)
#define NWX   (4 * 48 * DI)       // x_proj elements (4 layers)

typedef short bh8 __attribute__((ext_vector_type(8)));
typedef float f4x __attribute__((ext_vector_type(4)));

#define MFMA16 __builtin_amdgcn_mfma_f32_16x16x32_bf16

__device__ __forceinline__ float silu_f(float x) { return x / (1.f + __expf(-x)); }
__device__ __forceinline__ float softplus_f(float x) {
    return (x > 20.f) ? x : __logf(1.f + __expf(x));
}

__device__ __forceinline__ unsigned short f2bf(float f) {
    unsigned u = __float_as_uint(f);
    unsigned r = u + 0x7FFFu + ((u >> 16) & 1u);
    return (unsigned short)(r >> 16);
}
__device__ __forceinline__ float bf2f(unsigned short s) {
    return __uint_as_float(((unsigned)s) << 16);
}
__device__ __forceinline__ void split4s(float4 v, short4& h, short4& l) {
    unsigned short s;
    s = f2bf(v.x); h.x = (short)s; l.x = (short)f2bf(v.x - bf2f(s));
    s = f2bf(v.y); h.y = (short)s; l.y = (short)f2bf(v.y - bf2f(s));
    s = f2bf(v.z); h.z = (short)s; l.z = (short)f2bf(v.z - bf2f(s));
    s = f2bf(v.w); h.w = (short)s; l.w = (short)f2bf(v.w - bf2f(s));
}

// ---------------------------------------------------------------------------
// in_proj MFMA GEMM (3xbf16). BM=128, BN=64, K=256. grid (16,32) = 512 blocks.
// B (in_proj W) is ALWAYS read fp32 and split per-tile during LDS staging
// (~100 VALU/k-step, hidden under MFMA; proven in r5 step-0).
// AMAP 1 (step 0): A = x (fp32, g-dependent time reversal), plus a one-time
//   grid-stride epilogue pre-splitting out_proj + x_proj (5.2 MB, not 13 MB).
// AMAP 0 (step 1): A = Pout as pre-split bf16 hi/lo pairs.
// ---------------------------------------------------------------------------
template<int AMAP>
__global__ __launch_bounds__(256) void mfma_inproj(
    const float* __restrict__ Ax,
    const short* __restrict__ APh, const short* __restrict__ APl,
    const float* __restrict__ WinF,
    int step, float* __restrict__ C,
    const float* __restrict__ cvtB, short* __restrict__ cBh, short* __restrict__ cBl, int n4b,
    const float* __restrict__ cvtC, short* __restrict__ cCh, short* __restrict__ cCl, int n4c)
{
    constexpr int BM = 128, Ktot = DM, Nout = 2 * DI, ldc = 1024;
    __shared__ short As_hi[BM * 40];
    __shared__ short As_lo[BM * 40];
    __shared__ short Bs_hi[64 * 40];
    __shared__ short Bs_lo[64 * 40];

    const int row0 = blockIdx.y * BM;
    const int col0 = blockIdx.x * 64;
    const int g    = row0 >> 11;
    const int lay  = g * 2 + step;
    const float* WFg = WinF + (size_t)lay * Nout * Ktot;
    const int t    = threadIdx.x;
    const int lane = t & 63, wv = t >> 6;
    const int m = lane & 15, quad = lane >> 4;
    const int wr = wv >> 1, wc = wv & 1;
    const int NT = Ktot / 32;     // 8

    float4 pa[4];
    short4 pah[4], pal[4];
    float4 pbf[2];
    auto loadT = [&](int kt) {
        const int kb = kt * 32;
        #pragma unroll
        for (int i = 0; i < 4; i++) {
            int id = t + 256 * i;
            int row = id >> 3, kq = id & 7;
            if (AMAP == 1) {
                int gr = row0 + row;
                int gg = gr >> 11, b = (gr >> 10) & 1, l = gr & 1023;
                int sl = gg ? (1023 - l) : l;
                pa[i] = *(const float4*)&Ax[(size_t)(b * 1024 + sl) * Ktot + kb + kq * 4];
            } else {
                size_t o = (size_t)(row0 + row) * Ktot + kb + kq * 4;
                pah[i] = *(const short4*)&APh[o];
                pal[i] = *(const short4*)&APl[o];
            }
        }
        #pragma unroll
        for (int i = 0; i < 2; i++) {
            int id = t + 256 * i;
            int row = id >> 3, kq = id & 7;
            pbf[i] = *(const float4*)&WFg[(size_t)(col0 + row) * Ktot + kb + kq * 4];
        }
    };

    f4x acc[4][2] = {};
    loadT(0);

    for (int kt = 0; kt < NT; kt++) {
        #pragma unroll
        for (int i = 0; i < 4; i++) {
            int id = t + 256 * i;
            int row = id >> 3, kq = id & 7;
            if (AMAP == 1) {
                short4 h4, l4; split4s(pa[i], h4, l4);
                *(short4*)&As_hi[row * 40 + kq * 4] = h4;
                *(short4*)&As_lo[row * 40 + kq * 4] = l4;
            } else {
                *(short4*)&As_hi[row * 40 + kq * 4] = pah[i];
                *(short4*)&As_lo[row * 40 + kq * 4] = pal[i];
            }
        }
        #pragma unroll
        for (int i = 0; i < 2; i++) {
            int id = t + 256 * i;
            int row = id >> 3, kq = id & 7;
            short4 h4, l4; split4s(pbf[i], h4, l4);
            *(short4*)&Bs_hi[row * 40 + kq * 4] = h4;
            *(short4*)&Bs_lo[row * 40 + kq * 4] = l4;
        }
        __syncthreads();
        if (kt + 1 < NT) loadT(kt + 1);

        bh8 ah[4], al[4], bh[2], bl[2];
        #pragma unroll
        for (int p = 0; p < 4; p++) {
            int r = wr * 64 + p * 16 + m;
            ah[p] = *(bh8*)&As_hi[r * 40 + quad * 8];
            al[p] = *(bh8*)&As_lo[r * 40 + quad * 8];
        }
        #pragma unroll
        for (int q = 0; q < 2; q++) {
            int r = wc * 32 + q * 16 + m;
            bh[q] = *(bh8*)&Bs_hi[r * 40 + quad * 8];
            bl[q] = *(bh8*)&Bs_lo[r * 40 + quad * 8];
        }
        #pragma unroll
        for (int p = 0; p < 4; p++)
            #pragma unroll
            for (int q = 0; q < 2; q++) {
                acc[p][q] = MFMA16(ah[p], bh[q], acc[p][q], 0, 0, 0);
                acc[p][q] = MFMA16(ah[p], bl[q], acc[p][q], 0, 0, 0);
                acc[p][q] = MFMA16(al[p], bh[q], acc[p][q], 0, 0, 0);
            }
        __syncthreads();
    }

    #pragma unroll
    for (int p = 0; p < 4; p++)
        #pragma unroll
        for (int q = 0; q < 2; q++) {
            int gcol = col0 + wc * 32 + q * 16 + m;
            #pragma unroll
            for (int r = 0; r < 4; r++) {
                int grow = row0 + wr * 64 + p * 16 + quad * 4 + r;
                C[(size_t)grow * ldc + gcol] = acc[p][q][r];
            }
        }

    // ---- one-time pre-split of out_proj + x_proj (step 0 only, 5.2 MB) ----
    if (AMAP == 1) {
        const int bid = blockIdx.y * 16 + blockIdx.x;      // 0..511
        const int ntot = n4b + n4c;
        for (int i = bid * 256 + t; i < ntot; i += 512 * 256) {
            int j = i; const float* W; short *H, *Lo;
            if (j < n4b) { W = cvtB; H = cBh; Lo = cBl; }
            else { j -= n4b; W = cvtC; H = cCh; Lo = cCl; }
            float4 v = *(const float4*)&W[(size_t)j * 4];
            short4 h4, l4; split4s(v, h4, l4);
            *(short4*)&H[(size_t)j * 4] = h4;
            *(short4*)&Lo[(size_t)j * 4] = l4;
        }
    }
}

// ---------------------------------------------------------------------------
// scanA2: conv+silu + x_proj GEMM (3xbf16 MFMA, split-K over 8 waves) + dt +
// chunk-local scan, one block per (gb, chunk). No XCb side-write (scanB
// recomputes conv from XZ). Writes DBLc (scanB) + Aprod/Hend (combine).
// ---------------------------------------------------------------------------
__global__ __launch_bounds__(512) void scanA2(
    const float* __restrict__ XZ, const float* __restrict__ cw,
    const float* __restrict__ cb,
    const short* __restrict__ Wxh, const short* __restrict__ Wxl,
    const float* __restrict__ A_log, const float* __restrict__ Wdt,
    const float* __restrict__ bdt,
    float* __restrict__ DBLc,
    float* __restrict__ Aprod, float* __restrict__ Hend, int step)
{
    __shared__ short xcH[CL * XSTR];
    __shared__ short xcL[CL * XSTR];
    __shared__ float part[8][CL][48];
    __shared__ float dbl[CL][48];

    const int blk = blockIdx.x;
    const int c  = blk & (CH - 1);
    const int gb = blk >> 6;
    const int g  = gb >> 1;
    const int lay = g * 2 + step;
    const int d  = threadIdx.x;          // channel 0..511
    const int r0 = gb * L + c * CL;

    // ---- depthwise conv + silu for channel d, rows r0..r0+CL-1 ----
    float4 w4 = *(const float4*)&cw[((size_t)lay * DI + d) * 4];
    float cbv = cb[(size_t)lay * DI + d];
    float xz[CL + 3];
    #pragma unroll
    for (int j = 0; j < CL + 3; j++) {
        int lr = c * CL + j - 3;                  // local row in sequence
        xz[j] = (lr < 0) ? 0.f : XZ[(size_t)(gb * L + lr) * 1024 + d];
    }
    float xc[CL];
    #pragma unroll
    for (int tt = 0; tt < CL; tt++) {
        float v = cbv + w4.x * xz[tt] + w4.y * xz[tt + 1]
                      + w4.z * xz[tt + 2] + w4.w * xz[tt + 3];
        v = silu_f(v);
        xc[tt] = v;
        unsigned short hs = f2bf(v);
        xcH[tt * XSTR + d] = (short)hs;
        xcL[tt * XSTR + d] = (short)f2bf(v - bf2f(hs));
    }
    __syncthreads();

    // ---- dbl[16][48] = xc[16][512] @ Wx^T : 3xbf16 MFMA, split-K=64/wave ----
    {
        const int lane = d & 63, wv = d >> 6;
        const int m = lane & 15, quad = lane >> 4;
        const int ks = wv * 64;
        const size_t wb = (size_t)lay * 48 * DI;
        f4x acc3[3] = {};
        #pragma unroll
        for (int kt = 0; kt < 2; kt++) {
            const int kb = ks + kt * 32 + quad * 8;
            bh8 ah = *(bh8*)&xcH[m * XSTR + kb];
            bh8 al = *(bh8*)&xcL[m * XSTR + kb];
            #pragma unroll
            for (int f = 0; f < 3; f++) {
                bh8 bh = *(const bh8*)&Wxh[wb + (size_t)(f * 16 + m) * DI + kb];
                bh8 bl = *(const bh8*)&Wxl[wb + (size_t)(f * 16 + m) * DI + kb];
                acc3[f] = MFMA16(ah, bh, acc3[f], 0, 0, 0);
                acc3[f] = MFMA16(ah, bl, acc3[f], 0, 0, 0);
                acc3[f] = MFMA16(al, bh, acc3[f], 0, 0, 0);
            }
        }
        #pragma unroll
        for (int f = 0; f < 3; f++)
            #pragma unroll
            for (int r = 0; r < 4; r++)
                part[wv][quad * 4 + r][f * 16 + m] = acc3[f][r];
    }
    __syncthreads();

    for (int o = d; o < CL * 48; o += 512) {
        int tt = o / 48, cc = o - tt * 48;
        float v = 0.f;
        #pragma unroll
        for (int w = 0; w < 8; w++) v += part[w][tt][cc];
        dbl[tt][cc] = v;
        DBLc[(size_t)(r0 + tt) * 48 + cc] = v;    // compact side-write for scanB
    }

    // ---- dt + chunk-local scan ----
    float wdt[16];
    const float* wrow = Wdt + ((size_t)lay * DI + d) * DR;
    #pragma unroll
    for (int k = 0; k < 16; k += 4) {
        float4 v = *(const float4*)&wrow[k];
        wdt[k] = v.x; wdt[k + 1] = v.y; wdt[k + 2] = v.z; wdt[k + 3] = v.w;
    }
    float bias = bdt[(size_t)lay * DI + d];

    float a[DS], h[DS], ap[DS];
    const float* al = A_log + ((size_t)lay * DI + d) * DS;
    #pragma unroll
    for (int s = 0; s < DS; s++) { a[s] = -__expf(al[s]); h[s] = 0.f; ap[s] = 1.f; }
    __syncthreads();

    for (int tt = 0; tt < CL; tt++) {
        float dtr = bias;
        #pragma unroll
        for (int k = 0; k < 16; k++) dtr += dbl[tt][k] * wdt[k];
        float dt = softplus_f(dtr);
        float dx = dt * xc[tt];
        #pragma unroll
        for (int s = 0; s < DS; s++) {
            float da = __expf(dt * a[s]);
            h[s] = da * h[s] + dx * dbl[tt][16 + s];
            ap[s] *= da;
        }
    }
    size_t base = ((size_t)(gb * DI + d) * CH + c) * DS;
    #pragma unroll
    for (int q = 0; q < 4; q++) {
        *(float4*)&Aprod[base + q * 4] = make_float4(ap[q*4], ap[q*4+1], ap[q*4+2], ap[q*4+3]);
        *(float4*)&Hend [base + q * 4] = make_float4(h[q*4],  h[q*4+1],  h[q*4+2],  h[q*4+3]);
    }
}

// ---------------------------------------------------------------------------
// Combine: serial exclusive scan over CH chunks per (gb,d,s) lane. (unchanged)
// ---------------------------------------------------------------------------
__global__ __launch_bounds__(256) void scanCombine(
    const float* __restrict__ Aprod, const float* __restrict__ Hend,
    float* __restrict__ Hinit)
{
    int idx = blockIdx.x * 256 + threadIdx.x;  // (gb*DI+d)*DS + s
    int s  = idx & 15;
    int gd = idx >> 4;
    size_t base = (size_t)gd * CH * DS + s;
    float h = 0.f;
    for (int c0 = 0; c0 < CH; c0 += 8) {
        float ap[8], e[8];
        #pragma unroll
        for (int j = 0; j < 8; j++) {
            size_t o = base + (size_t)(c0 + j) * DS;
            ap[j] = Aprod[o]; e[j] = Hend[o];
        }
        #pragma unroll
        for (int j = 0; j < 8; j++) {
            Hinit[base + (size_t)(c0 + j) * DS] = h;
            h = ap[j] * h + e[j];
        }
    }
}

// ---------------------------------------------------------------------------
// Scan phase B + FUSED out_proj: recomputes conv+silu from XZ (bit-identical
// to scanA2 - no XCb buffer), dbl from compact DBLc, replay with h_init,
// y -> LDS (bf16 hi/lo), per-wave 3xbf16 MFMA epilogue with pre-split Wo rows.
// OUTMODE 0: write Pout as bf16 hi/lo pairs. OUTMODE 1: scatter fp32 to out.
// ---------------------------------------------------------------------------
template<int OUTMODE>
__global__ __launch_bounds__(512) void scanB_fused(
    const float* __restrict__ XZ, const float* __restrict__ DBLc,
    const float* __restrict__ cw, const float* __restrict__ cb,
    const float* __restrict__ A_log,
    const float* __restrict__ Wdt, const float* __restrict__ bdt,
    const float* __restrict__ Dp, const float* __restrict__ Hinit,
    const short* __restrict__ Woh, const short* __restrict__ Wol,
    float* __restrict__ Cout, short* __restrict__ Ph, short* __restrict__ Pl,
    int step)
{
    __shared__ float dbl[CL][48];
    __shared__ short Ys_hi[CL * YSTR];
    __shared__ short Ys_lo[CL * YSTR];
    int blk = blockIdx.x;
    int c  = blk & (CH - 1);
    int gb = blk >> 6;
    int g  = gb >> 1;
    int lay = g * 2 + step;
    int d = threadIdx.x;
    int r0 = gb * L + c * CL;

    for (int id = threadIdx.x; id < CL * 48; id += 512) {
        int rr = id / 48, cc = id - rr * 48;
        dbl[rr][cc] = DBLc[(size_t)(r0 + rr) * 48 + cc];
    }

    // ---- recompute conv + silu (bit-identical to scanA2) ----
    float4 w4 = *(const float4*)&cw[((size_t)lay * DI + d) * 4];
    float cbv = cb[(size_t)lay * DI + d];
    float xzv[CL + 3];
    #pragma unroll
    for (int j = 0; j < CL + 3; j++) {
        int lr = c * CL + j - 3;
        xzv[j] = (lr < 0) ? 0.f : XZ[(size_t)(gb * L + lr) * 1024 + d];
    }
    float xc[CL], zz[CL];
    #pragma unroll
    for (int tt = 0; tt < CL; tt++) {
        float v = cbv + w4.x * xzv[tt] + w4.y * xzv[tt + 1]
                      + w4.z * xzv[tt + 2] + w4.w * xzv[tt + 3];
        xc[tt] = silu_f(v);
    }
    #pragma unroll
    for (int tt = 0; tt < CL; tt++) zz[tt] = XZ[(size_t)(r0 + tt) * 1024 + 512 + d];

    float wdt[16];
    const float* wrow = Wdt + ((size_t)lay * DI + d) * DR;
    #pragma unroll
    for (int k = 0; k < 16; k += 4) {
        float4 v = *(const float4*)&wrow[k];
        wdt[k] = v.x; wdt[k + 1] = v.y; wdt[k + 2] = v.z; wdt[k + 3] = v.w;
    }
    float bias = bdt[(size_t)lay * DI + d];

    float a[DS], h[DS];
    const float* al = A_log + ((size_t)lay * DI + d) * DS;
    size_t base = ((size_t)(gb * DI + d) * CH + c) * DS;
    #pragma unroll
    for (int q = 0; q < 4; q++) {
        float4 hv = *(const float4*)&Hinit[base + q * 4];
        h[q*4] = hv.x; h[q*4+1] = hv.y; h[q*4+2] = hv.z; h[q*4+3] = hv.w;
    }
    #pragma unroll
    for (int s = 0; s < DS; s++) a[s] = -__expf(al[s]);
    float Dv = Dp[(size_t)lay * DI + d];
    __syncthreads();

    #pragma unroll
    for (int tt = 0; tt < CL; tt++) {
        float dtr = bias;
        #pragma unroll
        for (int k = 0; k < 16; k++) dtr += dbl[tt][k] * wdt[k];
        float dt = softplus_f(dtr);
        float dx = dt * xc[tt];
        float y = 0.f;
        #pragma unroll
        for (int s = 0; s < DS; s++) {
            float da = __expf(dt * a[s]);
            h[s] = da * h[s] + dx * dbl[tt][16 + s];
            y += h[s] * dbl[tt][32 + s];
        }
        y += xc[tt] * Dv;
        y *= silu_f(zz[tt]);
        unsigned short hs = f2bf(y);
        Ys_hi[tt * YSTR + d] = (short)hs;
        Ys_lo[tt * YSTR + d] = (short)f2bf(y - bf2f(hs));
    }
    __syncthreads();

    // ---- fused out_proj epilogue: 16 rows x 256 cols, K=512 ----
    const int lane = threadIdx.x & 63, wv = threadIdx.x >> 6;
    const int m = lane & 15, quad = lane >> 4;
    const size_t wbase = (size_t)lay * DM * DI;

    #pragma unroll
    for (int q = 0; q < 2; q++) {
        const int coln = wv * 32 + q * 16 + m;
        const size_t wrow2 = wbase + (size_t)coln * DI;
        bh8 wh[16], wl[16];
        #pragma unroll
        for (int i = 0; i < 16; i++) {
            const int kk = i * 32 + quad * 8;
            wh[i] = *(const bh8*)&Woh[wrow2 + kk];
            wl[i] = *(const bh8*)&Wol[wrow2 + kk];
        }
        f4x acc = {};
        #pragma unroll
        for (int i = 0; i < 16; i++) {
            const int kk = i * 32 + quad * 8;
            bh8 ahv = *(bh8*)&Ys_hi[m * YSTR + kk];
            bh8 alv = *(bh8*)&Ys_lo[m * YSTR + kk];
            acc = MFMA16(ahv, wh[i], acc, 0, 0, 0);
            acc = MFMA16(ahv, wl[i], acc, 0, 0, 0);
            acc = MFMA16(alv, wh[i], acc, 0, 0, 0);
        }
        #pragma unroll
        for (int r = 0; r < 4; r++) {
            int tt = quad * 4 + r;
            int grow = r0 + tt;
            if (OUTMODE == 0) {
                size_t o = (size_t)grow * DM + coln;
                unsigned short hs = f2bf(acc[r]);
                Ph[o] = (short)hs;
                Pl[o] = (short)f2bf(acc[r] - bf2f(hs));
            } else {
                int b = (grow >> 10) & 1, l = grow & 1023;
                size_t dst = (g == 0)
                    ? ((size_t)(b * 1024 + l) * 512 + coln)
                    : ((size_t)(b * 1024 + (1023 - l)) * 512 + 256 + coln);
                Cout[dst] = acc[r];
            }
        }
    }
}

extern "C" void kernel_launch(void* const* d_in, const int* in_sizes, int n_in,
                              void* d_out, int out_size, void* d_ws, size_t ws_size,
                              hipStream_t stream)
{
    const float* x        = (const float*)d_in[0];
    const float* in_proj  = (const float*)d_in[1];
    const float* conv_w   = (const float*)d_in[2];
    const float* conv_b   = (const float*)d_in[3];
    const float* x_proj   = (const float*)d_in[4];
    const float* dt_proj  = (const float*)d_in[5];
    const float* dt_bias  = (const float*)d_in[6];
    const float* A_log    = (const float*)d_in[7];
    const float* Dp       = (const float*)d_in[8];
    const float* out_proj = (const float*)d_in[9];
    float* out = (float*)d_out;

    float* w = (float*)d_ws;
    size_t o = 0;
    float* XZ    = w + o; o += (size_t)RTOT * 1024;
    float* DBLc  = w + o; o += (size_t)RTOT * 48;
    float* Aprod = w + o; o += (size_t)G * BB * DI * CH * DS;
    float* Hend  = w + o; o += (size_t)G * BB * DI * CH * DS;
    float* Hinit = w + o; o += (size_t)G * BB * DI * CH * DS;
    short* Woh   = (short*)(w + o); o += NWOUT / 2;
    short* Wol   = (short*)(w + o); o += NWOUT / 2;
    short* Wxh   = (short*)(w + o); o += NWX / 2;
    short* Wxl   = (short*)(w + o); o += NWX / 2;
    short* Ph    = (short*)(w + o); o += (size_t)RTOT * DM / 2;
    short* Pl    = (short*)(w + o); o += (size_t)RTOT * DM / 2;
    (void)ws_size; (void)in_sizes; (void)n_in; (void)out_size;

    for (int step = 0; step < 2; step++) {
        // in_proj: 4096x1024, K=256, MFMA 3xbf16. 128x64 tiles -> 512 blocks.
        // B split from fp32 on the fly in both steps; step 0 also runs the
        // one-time out_proj/x_proj pre-split epilogue.
        if (step == 0)
            mfma_inproj<1><<<dim3(16, 32), 256, 0, stream>>>(
                x, nullptr, nullptr, in_proj, 0, XZ,
                out_proj, Woh, Wol, NWOUT / 4,
                x_proj, Wxh, Wxl, NWX / 4);
        else
            mfma_inproj<0><<<dim3(16, 32), 256, 0, stream>>>(
                nullptr, Ph, Pl, in_proj, 1, XZ,
                nullptr, nullptr, nullptr, 0,
                nullptr, nullptr, nullptr, 0);

        // fused conv+silu + x_proj MFMA + dt + chunk scan: 256 blocks.
        scanA2<<<G * BB * CH, 512, 0, stream>>>(
            XZ, conv_w, conv_b, Wxh, Wxl, A_log, dt_proj, dt_bias,
            DBLc, Aprod, Hend, step);

        scanCombine<<<(G * BB * DI * DS) / 256, 256, 0, stream>>>(Aprod, Hend, Hinit);

        if (step == 0)
            scanB_fused<0><<<G * BB * CH, 512, 0, stream>>>(
                XZ, DBLc, conv_w, conv_b, A_log, dt_proj, dt_bias, Dp, Hinit,
                Woh, Wol, nullptr, Ph, Pl, 0);
        else
            scanB_fused<1><<<G * BB * CH, 512, 0, stream>>>(
                XZ, DBLc, conv_w, conv_b, A_log, dt_proj, dt_bias, Dp, Hinit,
                Woh, Wol, out, nullptr, nullptr, 1);
    }
}

// Round 8
// 222.254 us; speedup vs baseline: 3.2010x; 1.0141x over previous
//
#include <hip/hip_runtime.h>
#include <math.h>

#define G 2
#define BB 2
#define L 1024
#define DM 256
#define DI 512
#define DS 16
#define DR 16
#define CH 64              // chunks per sequence
#define CL 16              // L / CH
#define RTOT (G*BB*L)      // 4096 rows per layer-step
#define YSTR 520           // Ys LDS row stride (shorts)
#define XSTR 520           // xc LDS row stride (shorts)

#define NWIN  (4 * 2 * DI * DM)   // in_proj elements (4 layers)
#define NWOUT (4 * DM * DI)       // out_proj elements
#define NWX   (4 * 48 * DI)       // x_proj elements (4 layers)

typedef short bh8 __attribute__((ext_vector_type(8)));
typedef float f4x __attribute__((ext_vector_type(4)));

#define MFMA16 __builtin_amdgcn_mfma_f32_16x16x32_bf16

__device__ __forceinline__ float silu_f(float x) { return x / (1.f + __expf(-x)); }
__device__ __forceinline__ float softplus_f(float x) {
    return (x > 20.f) ? x : __logf(1.f + __expf(x));
}

__device__ __forceinline__ unsigned short f2bf(float f) {
    unsigned u = __float_as_uint(f);
    unsigned r = u + 0x7FFFu + ((u >> 16) & 1u);
    return (unsigned short)(r >> 16);
}
__device__ __forceinline__ float bf2f(unsigned short s) {
    return __uint_as_float(((unsigned)s) << 16);
}
__device__ __forceinline__ void split4s(float4 v, short4& h, short4& l) {
    unsigned short s;
    s = f2bf(v.x); h.x = (short)s; l.x = (short)f2bf(v.x - bf2f(s));
    s = f2bf(v.y); h.y = (short)s; l.y = (short)f2bf(v.y - bf2f(s));
    s = f2bf(v.z); h.z = (short)s; l.z = (short)f2bf(v.z - bf2f(s));
    s = f2bf(v.w); h.w = (short)s; l.w = (short)f2bf(v.w - bf2f(s));
}

// ---------------------------------------------------------------------------
// in_proj MFMA GEMM (3xbf16). BM=128, BN=64, K=256. grid (16,32) = 512 blocks.
// DOUBLE-BUFFERED LDS: one __syncthreads per k-step (was two). 61.4 KB LDS,
// 2 blocks/CU (unchanged).
// AMAP 1 (step 0): A = x (fp32, time reversal), B = fp32 split on the fly;
//   epilogue: one-time pre-split of in/out/x_proj weights (13 MB).
// AMAP 0 (step 1): A = Pout pre-split bf16 hi/lo, B = pre-split Wih/Wil.
// ---------------------------------------------------------------------------
template<int AMAP>
__global__ __launch_bounds__(256) void mfma_inproj(
    const float* __restrict__ Ax,
    const short* __restrict__ APh, const short* __restrict__ APl,
    const float* __restrict__ WinF,
    const short* __restrict__ Wh, const short* __restrict__ Wl,
    int step, float* __restrict__ C,
    const float* __restrict__ cvtA, short* __restrict__ cAh, short* __restrict__ cAl, int n4a,
    const float* __restrict__ cvtB, short* __restrict__ cBh, short* __restrict__ cBl, int n4b,
    const float* __restrict__ cvtC, short* __restrict__ cCh, short* __restrict__ cCl, int n4c)
{
    constexpr int BM = 128, Ktot = DM, Nout = 2 * DI, ldc = 1024;
    __shared__ short As_hi[2][BM * 40];
    __shared__ short As_lo[2][BM * 40];
    __shared__ short Bs_hi[2][64 * 40];
    __shared__ short Bs_lo[2][64 * 40];

    const int row0 = blockIdx.y * BM;
    const int col0 = blockIdx.x * 64;
    const int g    = row0 >> 11;
    const int lay  = g * 2 + step;
    const short* Whg = Wh  + (size_t)lay * Nout * Ktot;
    const short* Wlg = Wl  + (size_t)lay * Nout * Ktot;
    const float* WFg = WinF + (size_t)lay * Nout * Ktot;
    const int t    = threadIdx.x;
    const int lane = t & 63, wv = t >> 6;
    const int m = lane & 15, quad = lane >> 4;
    const int wr = wv >> 1, wc = wv & 1;
    const int NT = Ktot / 32;     // 8

    float4 pa[4];
    short4 pah[4], pal[4], pbh[2], pbl[2];
    float4 pbf[2];
    auto loadT = [&](int kt) {
        const int kb = kt * 32;
        #pragma unroll
        for (int i = 0; i < 4; i++) {
            int id = t + 256 * i;
            int row = id >> 3, kq = id & 7;
            if (AMAP == 1) {
                int gr = row0 + row;
                int gg = gr >> 11, b = (gr >> 10) & 1, l = gr & 1023;
                int sl = gg ? (1023 - l) : l;
                pa[i] = *(const float4*)&Ax[(size_t)(b * 1024 + sl) * Ktot + kb + kq * 4];
            } else {
                size_t o = (size_t)(row0 + row) * Ktot + kb + kq * 4;
                pah[i] = *(const short4*)&APh[o];
                pal[i] = *(const short4*)&APl[o];
            }
        }
        #pragma unroll
        for (int i = 0; i < 2; i++) {
            int id = t + 256 * i;
            int row = id >> 3, kq = id & 7;
            if (AMAP == 1) {
                pbf[i] = *(const float4*)&WFg[(size_t)(col0 + row) * Ktot + kb + kq * 4];
            } else {
                size_t o = (size_t)(col0 + row) * Ktot + kb + kq * 4;
                pbh[i] = *(const short4*)&Whg[o];
                pbl[i] = *(const short4*)&Wlg[o];
            }
        }
    };
    auto storeT = [&](int buf) {
        #pragma unroll
        for (int i = 0; i < 4; i++) {
            int id = t + 256 * i;
            int row = id >> 3, kq = id & 7;
            if (AMAP == 1) {
                short4 h4, l4; split4s(pa[i], h4, l4);
                *(short4*)&As_hi[buf][row * 40 + kq * 4] = h4;
                *(short4*)&As_lo[buf][row * 40 + kq * 4] = l4;
            } else {
                *(short4*)&As_hi[buf][row * 40 + kq * 4] = pah[i];
                *(short4*)&As_lo[buf][row * 40 + kq * 4] = pal[i];
            }
        }
        #pragma unroll
        for (int i = 0; i < 2; i++) {
            int id = t + 256 * i;
            int row = id >> 3, kq = id & 7;
            if (AMAP == 1) {
                short4 h4, l4; split4s(pbf[i], h4, l4);
                *(short4*)&Bs_hi[buf][row * 40 + kq * 4] = h4;
                *(short4*)&Bs_lo[buf][row * 40 + kq * 4] = l4;
            } else {
                *(short4*)&Bs_hi[buf][row * 40 + kq * 4] = pbh[i];
                *(short4*)&Bs_lo[buf][row * 40 + kq * 4] = pbl[i];
            }
        }
    };

    f4x acc[4][2] = {};
    loadT(0);
    storeT(0);
    __syncthreads();

    for (int kt = 0; kt < NT; kt++) {
        const int cur = kt & 1;
        if (kt + 1 < NT) loadT(kt + 1);

        bh8 ah[4], al[4], bh[2], bl[2];
        #pragma unroll
        for (int p = 0; p < 4; p++) {
            int r = wr * 64 + p * 16 + m;
            ah[p] = *(bh8*)&As_hi[cur][r * 40 + quad * 8];
            al[p] = *(bh8*)&As_lo[cur][r * 40 + quad * 8];
        }
        #pragma unroll
        for (int q = 0; q < 2; q++) {
            int r = wc * 32 + q * 16 + m;
            bh[q] = *(bh8*)&Bs_hi[cur][r * 40 + quad * 8];
            bl[q] = *(bh8*)&Bs_lo[cur][r * 40 + quad * 8];
        }
        #pragma unroll
        for (int p = 0; p < 4; p++)
            #pragma unroll
            for (int q = 0; q < 2; q++) {
                acc[p][q] = MFMA16(ah[p], bh[q], acc[p][q], 0, 0, 0);
                acc[p][q] = MFMA16(ah[p], bl[q], acc[p][q], 0, 0, 0);
                acc[p][q] = MFMA16(al[p], bh[q], acc[p][q], 0, 0, 0);
            }

        if (kt + 1 < NT) storeT(cur ^ 1);   // write NEXT tile into other buffer
        __syncthreads();                     // single barrier per k-step
    }

    #pragma unroll
    for (int p = 0; p < 4; p++)
        #pragma unroll
        for (int q = 0; q < 2; q++) {
            int gcol = col0 + wc * 32 + q * 16 + m;
            #pragma unroll
            for (int r = 0; r < 4; r++) {
                int grow = row0 + wr * 64 + p * 16 + quad * 4 + r;
                C[(size_t)grow * ldc + gcol] = acc[p][q][r];
            }
        }

    // ---- folded one-time weight conversion (step 0 only) ----
    if (AMAP == 1) {
        const int bid = blockIdx.y * 16 + blockIdx.x;      // 0..511
        const int ntot = n4a + n4b + n4c;
        for (int i = bid * 256 + t; i < ntot; i += 512 * 256) {
            int j = i; const float* W; short *H, *Lo;
            if (j < n4a) { W = cvtA; H = cAh; Lo = cAl; }
            else if (j < n4a + n4b) { j -= n4a; W = cvtB; H = cBh; Lo = cBl; }
            else { j -= n4a + n4b; W = cvtC; H = cCh; Lo = cCl; }
            float4 v = *(const float4*)&W[(size_t)j * 4];
            short4 h4, l4; split4s(v, h4, l4);
            *(short4*)&H[(size_t)j * 4] = h4;
            *(short4*)&Lo[(size_t)j * 4] = l4;
        }
    }
}

// ---------------------------------------------------------------------------
// scanA2: conv+silu + x_proj GEMM (3xbf16 MFMA, split-K over 8 waves) + dt +
// chunk-local scan, one block per (gb, chunk). Pre-split Wxh/Wxl.
// Writes XCb (for scanB), DBLc (for scanB), Aprod/Hend (combine).
// ---------------------------------------------------------------------------
__global__ __launch_bounds__(512) void scanA2(
    const float* __restrict__ XZ, const float* __restrict__ cw,
    const float* __restrict__ cb,
    const short* __restrict__ Wxh, const short* __restrict__ Wxl,
    const float* __restrict__ A_log, const float* __restrict__ Wdt,
    const float* __restrict__ bdt,
    float* __restrict__ XCb, float* __restrict__ DBLc,
    float* __restrict__ Aprod, float* __restrict__ Hend, int step)
{
    __shared__ short xcH[CL * XSTR];
    __shared__ short xcL[CL * XSTR];
    __shared__ float part[8][CL][48];
    __shared__ float dbl[CL][48];

    const int blk = blockIdx.x;
    const int c  = blk & (CH - 1);
    const int gb = blk >> 6;
    const int g  = gb >> 1;
    const int lay = g * 2 + step;
    const int d  = threadIdx.x;          // channel 0..511
    const int r0 = gb * L + c * CL;

    // ---- depthwise conv + silu for channel d, rows r0..r0+CL-1 ----
    float4 w4 = *(const float4*)&cw[((size_t)lay * DI + d) * 4];
    float cbv = cb[(size_t)lay * DI + d];
    float xz[CL + 3];
    #pragma unroll
    for (int j = 0; j < CL + 3; j++) {
        int lr = c * CL + j - 3;                  // local row in sequence
        xz[j] = (lr < 0) ? 0.f : XZ[(size_t)(gb * L + lr) * 1024 + d];
    }
    float xc[CL];
    #pragma unroll
    for (int tt = 0; tt < CL; tt++) {
        float v = cbv + w4.x * xz[tt] + w4.y * xz[tt + 1]
                      + w4.z * xz[tt + 2] + w4.w * xz[tt + 3];
        v = silu_f(v);
        xc[tt] = v;
        XCb[(size_t)(r0 + tt) * DI + d] = v;      // side product for scanB
        unsigned short hs = f2bf(v);
        xcH[tt * XSTR + d] = (short)hs;
        xcL[tt * XSTR + d] = (short)f2bf(v - bf2f(hs));
    }
    __syncthreads();

    // ---- dbl[16][48] = xc[16][512] @ Wx^T : 3xbf16 MFMA, split-K=64/wave ----
    {
        const int lane = d & 63, wv = d >> 6;
        const int m = lane & 15, quad = lane >> 4;
        const int ks = wv * 64;
        const size_t wb = (size_t)lay * 48 * DI;
        f4x acc3[3] = {};
        #pragma unroll
        for (int kt = 0; kt < 2; kt++) {
            const int kb = ks + kt * 32 + quad * 8;
            bh8 ah = *(bh8*)&xcH[m * XSTR + kb];
            bh8 al = *(bh8*)&xcL[m * XSTR + kb];
            #pragma unroll
            for (int f = 0; f < 3; f++) {
                bh8 bh = *(const bh8*)&Wxh[wb + (size_t)(f * 16 + m) * DI + kb];
                bh8 bl = *(const bh8*)&Wxl[wb + (size_t)(f * 16 + m) * DI + kb];
                acc3[f] = MFMA16(ah, bh, acc3[f], 0, 0, 0);
                acc3[f] = MFMA16(ah, bl, acc3[f], 0, 0, 0);
                acc3[f] = MFMA16(al, bh, acc3[f], 0, 0, 0);
            }
        }
        #pragma unroll
        for (int f = 0; f < 3; f++)
            #pragma unroll
            for (int r = 0; r < 4; r++)
                part[wv][quad * 4 + r][f * 16 + m] = acc3[f][r];
    }
    __syncthreads();

    for (int o = d; o < CL * 48; o += 512) {
        int tt = o / 48, cc = o - tt * 48;
        float v = 0.f;
        #pragma unroll
        for (int w = 0; w < 8; w++) v += part[w][tt][cc];
        dbl[tt][cc] = v;
        DBLc[(size_t)(r0 + tt) * 48 + cc] = v;    // compact side-write for scanB
    }

    // ---- dt + chunk-local scan ----
    float wdt[16];
    const float* wrow = Wdt + ((size_t)lay * DI + d) * DR;
    #pragma unroll
    for (int k = 0; k < 16; k += 4) {
        float4 v = *(const float4*)&wrow[k];
        wdt[k] = v.x; wdt[k + 1] = v.y; wdt[k + 2] = v.z; wdt[k + 3] = v.w;
    }
    float bias = bdt[(size_t)lay * DI + d];

    float a[DS], h[DS], ap[DS];
    const float* al = A_log + ((size_t)lay * DI + d) * DS;
    #pragma unroll
    for (int s = 0; s < DS; s++) { a[s] = -__expf(al[s]); h[s] = 0.f; ap[s] = 1.f; }
    __syncthreads();

    for (int tt = 0; tt < CL; tt++) {
        float dtr = bias;
        #pragma unroll
        for (int k = 0; k < 16; k++) dtr += dbl[tt][k] * wdt[k];
        float dt = softplus_f(dtr);
        float dx = dt * xc[tt];
        #pragma unroll
        for (int s = 0; s < DS; s++) {
            float da = __expf(dt * a[s]);
            h[s] = da * h[s] + dx * dbl[tt][16 + s];
            ap[s] *= da;
        }
    }
    size_t base = ((size_t)(gb * DI + d) * CH + c) * DS;
    #pragma unroll
    for (int q = 0; q < 4; q++) {
        *(float4*)&Aprod[base + q * 4] = make_float4(ap[q*4], ap[q*4+1], ap[q*4+2], ap[q*4+3]);
        *(float4*)&Hend [base + q * 4] = make_float4(h[q*4],  h[q*4+1],  h[q*4+2],  h[q*4+3]);
    }
}

// ---------------------------------------------------------------------------
// Combine: serial exclusive scan over CH chunks per (gb,d,s) lane. (unchanged)
// ---------------------------------------------------------------------------
__global__ __launch_bounds__(256) void scanCombine(
    const float* __restrict__ Aprod, const float* __restrict__ Hend,
    float* __restrict__ Hinit)
{
    int idx = blockIdx.x * 256 + threadIdx.x;  // (gb*DI+d)*DS + s
    int s  = idx & 15;
    int gd = idx >> 4;
    size_t base = (size_t)gd * CH * DS + s;
    float h = 0.f;
    for (int c0 = 0; c0 < CH; c0 += 8) {
        float ap[8], e[8];
        #pragma unroll
        for (int j = 0; j < 8; j++) {
            size_t o = base + (size_t)(c0 + j) * DS;
            ap[j] = Aprod[o]; e[j] = Hend[o];
        }
        #pragma unroll
        for (int j = 0; j < 8; j++) {
            Hinit[base + (size_t)(c0 + j) * DS] = h;
            h = ap[j] * h + e[j];
        }
    }
}

// ---------------------------------------------------------------------------
// Scan phase B + FUSED out_proj: dbl from compact DBLc, xc from XCb, replay
// with h_init, y -> LDS (bf16 hi/lo), per-wave 3xbf16 MFMA epilogue with
// register-preloaded pre-split weight rows.
// OUTMODE 0: write Pout as bf16 hi/lo pairs. OUTMODE 1: scatter fp32 to out.
// ---------------------------------------------------------------------------
template<int OUTMODE>
__global__ __launch_bounds__(512) void scanB_fused(
    const float* __restrict__ XCb, const float* __restrict__ DBLc,
    const float* __restrict__ XZ, const float* __restrict__ A_log,
    const float* __restrict__ Wdt, const float* __restrict__ bdt,
    const float* __restrict__ Dp, const float* __restrict__ Hinit,
    const short* __restrict__ Woh, const short* __restrict__ Wol,
    float* __restrict__ Cout, short* __restrict__ Ph, short* __restrict__ Pl,
    int step)
{
    __shared__ float dbl[CL][48];
    __shared__ short Ys_hi[CL * YSTR];
    __shared__ short Ys_lo[CL * YSTR];
    int blk = blockIdx.x;
    int c  = blk & (CH - 1);
    int gb = blk >> 6;
    int g  = gb >> 1;
    int lay = g * 2 + step;
    int d = threadIdx.x;
    int r0 = gb * L + c * CL;

    for (int id = threadIdx.x; id < CL * 48; id += 512) {
        int rr = id / 48, cc = id - rr * 48;
        dbl[rr][cc] = DBLc[(size_t)(r0 + rr) * 48 + cc];
    }

    float xc[CL], zz[CL];
    #pragma unroll
    for (int tt = 0; tt < CL; tt++) xc[tt] = XCb[(size_t)(r0 + tt) * DI + d];
    #pragma unroll
    for (int tt = 0; tt < CL; tt++) zz[tt] = XZ[(size_t)(r0 + tt) * 1024 + 512 + d];

    float wdt[16];
    const float* wrow = Wdt + ((size_t)lay * DI + d) * DR;
    #pragma unroll
    for (int k = 0; k < 16; k += 4) {
        float4 v = *(const float4*)&wrow[k];
        wdt[k] = v.x; wdt[k + 1] = v.y; wdt[k + 2] = v.z; wdt[k + 3] = v.w;
    }
    float bias = bdt[(size_t)lay * DI + d];

    float a[DS], h[DS];
    const float* al = A_log + ((size_t)lay * DI + d) * DS;
    size_t base = ((size_t)(gb * DI + d) * CH + c) * DS;
    #pragma unroll
    for (int q = 0; q < 4; q++) {
        float4 hv = *(const float4*)&Hinit[base + q * 4];
        h[q*4] = hv.x; h[q*4+1] = hv.y; h[q*4+2] = hv.z; h[q*4+3] = hv.w;
    }
    #pragma unroll
    for (int s = 0; s < DS; s++) a[s] = -__expf(al[s]);
    float Dv = Dp[(size_t)lay * DI + d];
    __syncthreads();

    #pragma unroll
    for (int tt = 0; tt < CL; tt++) {
        float dtr = bias;
        #pragma unroll
        for (int k = 0; k < 16; k++) dtr += dbl[tt][k] * wdt[k];
        float dt = softplus_f(dtr);
        float dx = dt * xc[tt];
        float y = 0.f;
        #pragma unroll
        for (int s = 0; s < DS; s++) {
            float da = __expf(dt * a[s]);
            h[s] = da * h[s] + dx * dbl[tt][16 + s];
            y += h[s] * dbl[tt][32 + s];
        }
        y += xc[tt] * Dv;
        y *= silu_f(zz[tt]);
        unsigned short hs = f2bf(y);
        Ys_hi[tt * YSTR + d] = (short)hs;
        Ys_lo[tt * YSTR + d] = (short)f2bf(y - bf2f(hs));
    }
    __syncthreads();

    // ---- fused out_proj epilogue: 16 rows x 256 cols, K=512 ----
    const int lane = threadIdx.x & 63, wv = threadIdx.x >> 6;
    const int m = lane & 15, quad = lane >> 4;
    const size_t wbase = (size_t)lay * DM * DI;

    #pragma unroll
    for (int q = 0; q < 2; q++) {
        const int coln = wv * 32 + q * 16 + m;
        const size_t wrow2 = wbase + (size_t)coln * DI;
        bh8 wh[16], wl[16];
        #pragma unroll
        for (int i = 0; i < 16; i++) {
            const int kk = i * 32 + quad * 8;
            wh[i] = *(const bh8*)&Woh[wrow2 + kk];
            wl[i] = *(const bh8*)&Wol[wrow2 + kk];
        }
        f4x acc = {};
        #pragma unroll
        for (int i = 0; i < 16; i++) {
            const int kk = i * 32 + quad * 8;
            bh8 ahv = *(bh8*)&Ys_hi[m * YSTR + kk];
            bh8 alv = *(bh8*)&Ys_lo[m * YSTR + kk];
            acc = MFMA16(ahv, wh[i], acc, 0, 0, 0);
            acc = MFMA16(ahv, wl[i], acc, 0, 0, 0);
            acc = MFMA16(alv, wh[i], acc, 0, 0, 0);
        }
        #pragma unroll
        for (int r = 0; r < 4; r++) {
            int tt = quad * 4 + r;
            int grow = r0 + tt;
            if (OUTMODE == 0) {
                size_t o = (size_t)grow * DM + coln;
                unsigned short hs = f2bf(acc[r]);
                Ph[o] = (short)hs;
                Pl[o] = (short)f2bf(acc[r] - bf2f(hs));
            } else {
                int b = (grow >> 10) & 1, l = grow & 1023;
                size_t dst = (g == 0)
                    ? ((size_t)(b * 1024 + l) * 512 + coln)
                    : ((size_t)(b * 1024 + (1023 - l)) * 512 + 256 + coln);
                Cout[dst] = acc[r];
            }
        }
    }
}

extern "C" void kernel_launch(void* const* d_in, const int* in_sizes, int n_in,
                              void* d_out, int out_size, void* d_ws, size_t ws_size,
                              hipStream_t stream)
{
    const float* x        = (const float*)d_in[0];
    const float* in_proj  = (const float*)d_in[1];
    const float* conv_w   = (const float*)d_in[2];
    const float* conv_b   = (const float*)d_in[3];
    const float* x_proj   = (const float*)d_in[4];
    const float* dt_proj  = (const float*)d_in[5];
    const float* dt_bias  = (const float*)d_in[6];
    const float* A_log    = (const float*)d_in[7];
    const float* Dp       = (const float*)d_in[8];
    const float* out_proj = (const float*)d_in[9];
    float* out = (float*)d_out;

    float* w = (float*)d_ws;
    size_t o = 0;
    float* XZ    = w + o; o += (size_t)RTOT * 1024;
    float* XCb   = w + o; o += (size_t)RTOT * DI;
    float* DBLc  = w + o; o += (size_t)RTOT * 48;
    float* Aprod = w + o; o += (size_t)G * BB * DI * CH * DS;
    float* Hend  = w + o; o += (size_t)G * BB * DI * CH * DS;
    float* Hinit = w + o; o += (size_t)G * BB * DI * CH * DS;
    short* Wih   = (short*)(w + o); o += NWIN / 2;
    short* Wil   = (short*)(w + o); o += NWIN / 2;
    short* Woh   = (short*)(w + o); o += NWOUT / 2;
    short* Wol   = (short*)(w + o); o += NWOUT / 2;
    short* Wxh   = (short*)(w + o); o += NWX / 2;
    short* Wxl   = (short*)(w + o); o += NWX / 2;
    short* Ph    = (short*)(w + o); o += (size_t)RTOT * DM / 2;
    short* Pl    = (short*)(w + o); o += (size_t)RTOT * DM / 2;
    (void)ws_size; (void)in_sizes; (void)n_in; (void)out_size;

    for (int step = 0; step < 2; step++) {
        // in_proj: 4096x1024, K=256, MFMA 3xbf16. 128x64 tiles -> 512 blocks.
        // Step 0 additionally performs the one-time weight pre-split epilogue.
        if (step == 0)
            mfma_inproj<1><<<dim3(16, 32), 256, 0, stream>>>(
                x, nullptr, nullptr, in_proj, nullptr, nullptr, 0, XZ,
                in_proj, Wih, Wil, NWIN / 4,
                out_proj, Woh, Wol, NWOUT / 4,
                x_proj, Wxh, Wxl, NWX / 4);
        else
            mfma_inproj<0><<<dim3(16, 32), 256, 0, stream>>>(
                nullptr, Ph, Pl, nullptr, Wih, Wil, 1, XZ,
                nullptr, nullptr, nullptr, 0,
                nullptr, nullptr, nullptr, 0,
                nullptr, nullptr, nullptr, 0);

        // fused conv+silu + x_proj MFMA + dt + chunk scan: 256 blocks.
        scanA2<<<G * BB * CH, 512, 0, stream>>>(
            XZ, conv_w, conv_b, Wxh, Wxl, A_log, dt_proj, dt_bias,
            XCb, DBLc, Aprod, Hend, step);

        scanCombine<<<(G * BB * DI * DS) / 256, 256, 0, stream>>>(Aprod, Hend, Hinit);

        if (step == 0)
            scanB_fused<0><<<G * BB * CH, 512, 0, stream>>>(
                XCb, DBLc, XZ, A_log, dt_proj, dt_bias, Dp, Hinit,
                Woh, Wol, nullptr, Ph, Pl, 0);
        else
            scanB_fused<1><<<G * BB * CH, 512, 0, stream>>>(
                XCb, DBLc, XZ, A_log, dt_proj, dt_bias, Dp, Hinit,
                Woh, Wol, out, nullptr, nullptr, 1);
    }
}